// Round 1
// baseline (12776.289 us; speedup 1.0000x reference)
//
#include <hip/hip_runtime.h>
#include <math.h>

// Problem constants
#define E_DIM   1024
#define H_HEADS 16
#define D_HEAD  64
#define F_DIM   4096
#define L_LAYERS 4
#define V_VOCAB 32000
#define B_BATCH 2
#define T_SEQ   2048
#define NROWS   (B_BATCH * T_SEQ)   // 4096
#define LN_EPS  1e-5f

// ---------------------------------------------------------------------------
// Embedding: h[b,t,:] = tok_emb[x[b,t]] + pos_emb[t]
// One float4 per thread; total float4 = NROWS*E/4 = 1,048,576 (exact).
// ---------------------------------------------------------------------------
__global__ __launch_bounds__(256) void embed_kernel(
    const int* __restrict__ x, const float* __restrict__ tok,
    const float* __restrict__ pos, float* __restrict__ h) {
  int i = blockIdx.x * 256 + threadIdx.x;   // float4 index
  int row = i >> 8;                         // / (E/4 = 256)
  int c = i & 255;
  int token = x[row];
  int t = row & (T_SEQ - 1);
  const float4* tok4 = (const float4*)tok;
  const float4* pos4 = (const float4*)pos;
  float4 a = tok4[(size_t)token * 256 + c];
  float4 b = pos4[(size_t)t * 256 + c];
  float4 o;
  o.x = a.x + b.x; o.y = a.y + b.y; o.z = a.z + b.z; o.w = a.w + b.w;
  ((float4*)h)[i] = o;
}

// ---------------------------------------------------------------------------
// LayerNorm: one 256-thread block per row of E=1024. float4 per thread.
// ---------------------------------------------------------------------------
__global__ __launch_bounds__(256) void ln_kernel(
    const float* __restrict__ in, float* __restrict__ out,
    const float* __restrict__ g, const float* __restrict__ b) {
  __shared__ float sm[4];
  int row = blockIdx.x;
  int tid = threadIdx.x;
  const float4* in4 = (const float4*)(in + (size_t)row * E_DIM);
  float4 x = in4[tid];

  float s = x.x + x.y + x.z + x.w;
  #pragma unroll
  for (int off = 32; off; off >>= 1) s += __shfl_down(s, off);
  if ((tid & 63) == 0) sm[tid >> 6] = s;
  __syncthreads();
  float mean = (sm[0] + sm[1] + sm[2] + sm[3]) * (1.0f / E_DIM);
  __syncthreads();

  float dx = x.x - mean, dy = x.y - mean, dz = x.z - mean, dw = x.w - mean;
  float v = dx * dx + dy * dy + dz * dz + dw * dw;
  #pragma unroll
  for (int off = 32; off; off >>= 1) v += __shfl_down(v, off);
  if ((tid & 63) == 0) sm[tid >> 6] = v;
  __syncthreads();
  float var = (sm[0] + sm[1] + sm[2] + sm[3]) * (1.0f / E_DIM);
  float rs = rsqrtf(var + LN_EPS);

  float4 gg = ((const float4*)g)[tid];
  float4 bb = ((const float4*)b)[tid];
  float4 o;
  o.x = dx * rs * gg.x + bb.x;
  o.y = dy * rs * gg.y + bb.y;
  o.z = dz * rs * gg.z + bb.z;
  o.w = dw * rs * gg.w + bb.w;
  ((float4*)(out + (size_t)row * E_DIM))[tid] = o;
}

// ---------------------------------------------------------------------------
// fp32 GEMM: C[M,N] = A[M,K] @ W[K,N] + bias (+resid) (+GELU)
// 128x128 block tile, BK=16, 256 threads, 8x8 per thread.
// Wave layout: 4 waves as 2x2 over the tile (64x64 each); lane 8x8 inside.
// LDS rows padded to 132 words -> 2-way-max bank aliasing on the b128 reads
// (free per m136). All dims divide tiles exactly (M=4096; N in {1024,4096,
// 32000}; K in {1024,4096}), so no bounds checks.
// ---------------------------------------------------------------------------
#define BM 128
#define BN 128
#define BK 16
#define LDP 132

__global__ __launch_bounds__(256) void gemm_kernel(
    const float* __restrict__ A, const float* __restrict__ W,
    const float* __restrict__ bias, const float* __restrict__ resid,
    float* __restrict__ C, int M, int N, int K, int gelu) {
  __shared__ float As[BK][LDP];  // [k][m] (transposed on store)
  __shared__ float Bs[BK][LDP];  // [k][n]

  int tid = threadIdx.x;
  int bm0 = blockIdx.y * BM;
  int bn0 = blockIdx.x * BN;

  int w = tid >> 6, l = tid & 63;
  int wr = w >> 1, wc = w & 1;
  int lr = l >> 3, lc = l & 7;
  int tr = wr * 64 + lr * 8;   // row offset of this thread's 8x8 in tile
  int tc = wc * 64 + lc * 8;

  float acc[8][8] = {};

  int la_row = tid >> 2;            // 0..63 (and +64)
  int la_col = (tid & 3) * 4;       // 0,4,8,12
  int lb_row = tid >> 5;            // 0..7 (and +8)
  int lb_col = (tid & 31) * 4;      // 0..124

  const float* Aptr = A + (size_t)(bm0 + la_row) * K + la_col;
  const float* Wptr = W + (size_t)lb_row * N + bn0 + lb_col;

  for (int k0 = 0; k0 < K; k0 += BK) {
    float4 a0 = *(const float4*)(Aptr + k0);
    float4 a1 = *(const float4*)(Aptr + (size_t)64 * K + k0);
    float4 b0 = *(const float4*)(Wptr + (size_t)k0 * N);
    float4 b1 = *(const float4*)(Wptr + (size_t)(k0 + 8) * N);

    __syncthreads();   // previous iteration's reads done
    As[la_col + 0][la_row] = a0.x;
    As[la_col + 1][la_row] = a0.y;
    As[la_col + 2][la_row] = a0.z;
    As[la_col + 3][la_row] = a0.w;
    As[la_col + 0][la_row + 64] = a1.x;
    As[la_col + 1][la_row + 64] = a1.y;
    As[la_col + 2][la_row + 64] = a1.z;
    As[la_col + 3][la_row + 64] = a1.w;
    *(float4*)&Bs[lb_row][lb_col] = b0;
    *(float4*)&Bs[lb_row + 8][lb_col] = b1;
    __syncthreads();

    #pragma unroll
    for (int kk = 0; kk < BK; ++kk) {
      float4 a03 = *(const float4*)&As[kk][tr];
      float4 a47 = *(const float4*)&As[kk][tr + 4];
      float4 b03 = *(const float4*)&Bs[kk][tc];
      float4 b47 = *(const float4*)&Bs[kk][tc + 4];
      float a[8] = {a03.x, a03.y, a03.z, a03.w, a47.x, a47.y, a47.z, a47.w};
      float b[8] = {b03.x, b03.y, b03.z, b03.w, b47.x, b47.y, b47.z, b47.w};
      #pragma unroll
      for (int i = 0; i < 8; ++i)
        #pragma unroll
        for (int j = 0; j < 8; ++j)
          acc[i][j] += a[i] * b[j];
    }
  }

  // epilogue: bias (+resid) (+gelu)
  #pragma unroll
  for (int i = 0; i < 8; ++i) {
    size_t rowbase = (size_t)(bm0 + tr + i) * N + bn0 + tc;
    #pragma unroll
    for (int j = 0; j < 8; ++j) {
      float vacc = acc[i][j] + bias[bn0 + tc + j];
      if (resid) vacc += resid[rowbase + j];
      if (gelu) vacc = 0.5f * vacc * (1.0f + erff(vacc * 0.70710678118654752f));
      C[rowbase + j] = vacc;
    }
  }
}

// ---------------------------------------------------------------------------
// Flash attention (causal), fp32. One block per (query-tile of 64, head, batch).
// 256 threads: thread = (r, c), r = query row in tile (0..63), c = key/d chunk
// owner (0..3, 16 elems each). K stored transposed in LDS ([d][k]) so the
// score inner loop reads contiguous float4s (2-way bank aliasing max).
// p exchanged through LDS within the same wave (lanes 4r..4r+3) -> no barrier.
// ---------------------------------------------------------------------------
__global__ __launch_bounds__(256) void attn_kernel(
    const float* __restrict__ Q, const float* __restrict__ Kg,
    const float* __restrict__ Vg, float* __restrict__ O) {
  __shared__ float qs[64][68];
  __shared__ float kst[64][68];   // [d][k]
  __shared__ float vs[64][68];    // [k][d]
  __shared__ float ps[64][68];    // [q][k]

  int qb = blockIdx.x;            // 0..31
  int h  = blockIdx.y;
  int b  = blockIdx.z;
  int tid = threadIdx.x;
  int r = tid >> 2;               // 0..63
  int c = tid & 3;
  int c16 = c * 16;
  int q0 = qb * 64;
  size_t base = (size_t)b * T_SEQ * E_DIM + h * 64;

  // load Q tile
  {
    int col = (tid & 15) * 4;
    #pragma unroll
    for (int i = 0; i < 4; ++i) {
      int rr = (tid >> 4) + i * 16;
      float4 qv = *(const float4*)(Q + base + (size_t)(q0 + rr) * E_DIM + col);
      *(float4*)&qs[rr][col] = qv;
    }
  }
  __syncthreads();

  float m = -INFINITY, lsum = 0.f;
  float o[16] = {};
  const float scale = 0.125f;     // 1/sqrt(64)

  for (int kt = 0; kt <= qb; ++kt) {
    int k0 = kt * 64;
    float4 kv[4], vv[4];
    int col = (tid & 15) * 4;
    #pragma unroll
    for (int i = 0; i < 4; ++i) {
      int rr = (tid >> 4) + i * 16;
      kv[i] = *(const float4*)(Kg + base + (size_t)(k0 + rr) * E_DIM + col);
      vv[i] = *(const float4*)(Vg + base + (size_t)(k0 + rr) * E_DIM + col);
    }
    __syncthreads();   // previous tile's LDS reads done
    #pragma unroll
    for (int i = 0; i < 4; ++i) {
      int rr = (tid >> 4) + i * 16;
      kst[col + 0][rr] = kv[i].x;
      kst[col + 1][rr] = kv[i].y;
      kst[col + 2][rr] = kv[i].z;
      kst[col + 3][rr] = kv[i].w;
      *(float4*)&vs[rr][col] = vv[i];
    }
    __syncthreads();

    float s[16];
    #pragma unroll
    for (int kk = 0; kk < 16; ++kk) s[kk] = 0.f;
    for (int d = 0; d < 64; ++d) {
      float qd = qs[r][d];
      #pragma unroll
      for (int kk = 0; kk < 16; ++kk) s[kk] += qd * kst[d][c16 + kk];
    }

    float mloc = -INFINITY;
    #pragma unroll
    for (int kk = 0; kk < 16; ++kk) {
      s[kk] *= scale;
      if (kt == qb && (c16 + kk) > r) s[kk] = -INFINITY;
      mloc = fmaxf(mloc, s[kk]);
    }
    mloc = fmaxf(mloc, __shfl_xor(mloc, 1));
    mloc = fmaxf(mloc, __shfl_xor(mloc, 2));
    float mnew = fmaxf(m, mloc);
    float alpha = __expf(m - mnew);   // first tile: exp(-inf)=0

    float psum = 0.f;
    #pragma unroll
    for (int kk = 0; kk < 16; ++kk) {
      float p = __expf(s[kk] - mnew);
      ps[r][c16 + kk] = p;
      psum += p;
    }
    psum += __shfl_xor(psum, 1);
    psum += __shfl_xor(psum, 2);
    lsum = lsum * alpha + psum;
    m = mnew;

    #pragma unroll
    for (int dd = 0; dd < 16; ++dd) o[dd] *= alpha;
    for (int k = 0; k < 64; ++k) {
      float pk = ps[r][k];   // same-wave write->read, no barrier needed
      #pragma unroll
      for (int dd = 0; dd < 16; ++dd) o[dd] += pk * vs[k][c16 + dd];
    }
  }

  float inv = 1.0f / lsum;
  size_t ob = base + (size_t)(q0 + r) * E_DIM + c16;
  #pragma unroll
  for (int dd = 0; dd < 16; ++dd) O[ob + dd] = o[dd] * inv;
}

// ---------------------------------------------------------------------------
// Orchestration
// ---------------------------------------------------------------------------
extern "C" void kernel_launch(void* const* d_in, const int* in_sizes, int n_in,
                              void* d_out, int out_size, void* d_ws, size_t ws_size,
                              hipStream_t stream) {
  const int*   x    = (const int*)  d_in[0];
  const float* tok  = (const float*)d_in[1];
  const float* pos  = (const float*)d_in[2];
  const float* Wq   = (const float*)d_in[3];
  const float* bq   = (const float*)d_in[4];
  const float* Wk   = (const float*)d_in[5];
  const float* bk   = (const float*)d_in[6];
  const float* Wv   = (const float*)d_in[7];
  const float* bv   = (const float*)d_in[8];
  const float* Wo   = (const float*)d_in[9];
  const float* bo   = (const float*)d_in[10];
  const float* ln1g = (const float*)d_in[11];
  const float* ln1b = (const float*)d_in[12];
  const float* W1   = (const float*)d_in[13];
  const float* b1   = (const float*)d_in[14];
  const float* W2   = (const float*)d_in[15];
  const float* b2   = (const float*)d_in[16];
  const float* ln2g = (const float*)d_in[17];
  const float* ln2b = (const float*)d_in[18];
  const float* lnfg = (const float*)d_in[19];
  const float* lnfb = (const float*)d_in[20];
  const float* Wout = (const float*)d_in[21];
  const float* bout = (const float*)d_in[22];
  float* out = (float*)d_out;

  // workspace layout (floats): 6 x [4096,1024] + 1 x [4096,4096] = ~168 MB
  float* ws = (float*)d_ws;
  const size_t SZ = (size_t)NROWS * E_DIM;
  float* h  = ws;
  float* xn = h  + SZ;
  float* q  = xn + SZ;
  float* k  = q  + SZ;
  float* v  = k  + SZ;
  float* ao = v  + SZ;
  float* ff = ao + SZ;    // NROWS * F_DIM

  embed_kernel<<<(NROWS * E_DIM / 4) / 256, 256, 0, stream>>>(x, tok, pos, h);

  dim3 gE(E_DIM / BN, NROWS / BM);   // (8, 32)
  dim3 gF(F_DIM / BN, NROWS / BM);   // (32, 32)
  dim3 gV(V_VOCAB / BN, NROWS / BM); // (250, 32)
  dim3 gA(T_SEQ / 64, H_HEADS, B_BATCH);

  for (int l = 0; l < L_LAYERS; ++l) {
    size_t wEE = (size_t)l * E_DIM * E_DIM;
    size_t wEF = (size_t)l * E_DIM * F_DIM;

    ln_kernel<<<NROWS, 256, 0, stream>>>(h, xn, ln1g + l * E_DIM, ln1b + l * E_DIM);
    gemm_kernel<<<gE, 256, 0, stream>>>(xn, Wq + wEE, bq + l * E_DIM, nullptr, q,
                                        NROWS, E_DIM, E_DIM, 0);
    gemm_kernel<<<gE, 256, 0, stream>>>(xn, Wk + wEE, bk + l * E_DIM, nullptr, k,
                                        NROWS, E_DIM, E_DIM, 0);
    gemm_kernel<<<gE, 256, 0, stream>>>(xn, Wv + wEE, bv + l * E_DIM, nullptr, v,
                                        NROWS, E_DIM, E_DIM, 0);
    attn_kernel<<<gA, 256, 0, stream>>>(q, k, v, ao);
    gemm_kernel<<<gE, 256, 0, stream>>>(ao, Wo + wEE, bo + l * E_DIM, h, h,
                                        NROWS, E_DIM, E_DIM, 0);
    ln_kernel<<<NROWS, 256, 0, stream>>>(h, xn, ln2g + l * E_DIM, ln2b + l * E_DIM);
    gemm_kernel<<<gF, 256, 0, stream>>>(xn, W1 + wEF, b1 + l * F_DIM, nullptr, ff,
                                        NROWS, F_DIM, E_DIM, 1);
    gemm_kernel<<<gE, 256, 0, stream>>>(ff, W2 + wEF, b2 + l * E_DIM, h, h,
                                        NROWS, E_DIM, F_DIM, 0);
  }

  ln_kernel<<<NROWS, 256, 0, stream>>>(h, xn, lnfg, lnfb);
  gemm_kernel<<<gV, 256, 0, stream>>>(xn, Wout, bout, nullptr, out,
                                      NROWS, V_VOCAB, E_DIM, 0);
}